// Round 10
// baseline (120.382 us; speedup 1.0000x reference)
//
#include <hip/hip_runtime.h>
#include <math.h>

typedef __attribute__((ext_vector_type(8))) short s16x8;
typedef __attribute__((ext_vector_type(4))) float f32x4;
typedef __attribute__((ext_vector_type(4))) unsigned int u32x4;

#define CCH 128
#define BSZ 32

// fp32 -> bf16 round-to-nearest-even (scalar)
static __device__ inline unsigned short f2bf(float f) {
    unsigned u = __float_as_uint(f);
    unsigned r = (u + 0x7FFFu + ((u >> 16) & 1u)) >> 16;
    return (unsigned short)r;
}

// packed f32x2 -> bf16x2 (RNE)
static __device__ inline unsigned cvtpk(float lo, float hi) {
    unsigned r;
    asm("v_cvt_pk_bf16_f32 %0, %1, %2" : "=v"(r) : "v"(lo), "v"(hi));
    return r;
}

// ================= BIG-WS PATH =================

// ---------------- prep: fused GAP + x->bf16 relayout ----------------
// grid 513 x 256. Block 512 zeroes the 4KB zero block.
// Block (b,cc,q): reads x[b, cc*32..+32, px-quarter q], writes
// xws[b][cc][px][oct(4)][8 bf16] (64B/px contiguous, coalesced) and
// per-quarter channel sums pooled2[b][q][128] (no atomics).
__global__ __launch_bounds__(256, 4) void prep_kernel(const float* __restrict__ x,
                                                      unsigned short* __restrict__ xws,
                                                      float* __restrict__ pooled2,
                                                      unsigned short* __restrict__ zeros) {
    int bid = blockIdx.x;
    int t = threadIdx.x;
    if (bid == 512) {
        u32x4 zq = {0u, 0u, 0u, 0u};
        *(u32x4*)&zeros[t * 8] = zq;
        return;
    }
    int b = bid >> 4, cc = (bid >> 2) & 3, q = bid & 3;
    const float* xb = x + ((size_t)b * CCH + cc * 32) * 4096;
    unsigned short* xo = xws + (((size_t)b * 4 + cc) * 4096) * 32;

    float sums[32];
#pragma unroll
    for (int c = 0; c < 32; ++c) sums[c] = 0.f;

#pragma unroll
    for (int j = 0; j < 4; ++j) {
        int px = q * 1024 + j * 256 + t;
        float v[32];
#pragma unroll
        for (int c = 0; c < 32; ++c) {
            v[c] = xb[(size_t)c * 4096 + px];
            sums[c] += v[c];
        }
        unsigned pw[16];
#pragma unroll
        for (int c2 = 0; c2 < 16; ++c2) pw[c2] = cvtpk(v[2 * c2], v[2 * c2 + 1]);
        unsigned short* dp = xo + (size_t)px * 32;
#pragma unroll
        for (int o = 0; o < 4; ++o) {
            u32x4 qv; qv[0] = pw[o*4+0]; qv[1] = pw[o*4+1]; qv[2] = pw[o*4+2]; qv[3] = pw[o*4+3];
            *(u32x4*)&dp[o * 8] = qv;
        }
    }
    // block-reduce the 32 channel sums
    __shared__ float red[4][32];
    int l = t & 63, wv = t >> 6;
#pragma unroll
    for (int c = 0; c < 32; ++c) {
        float s = sums[c];
        s += __shfl_xor(s, 1, 64); s += __shfl_xor(s, 2, 64); s += __shfl_xor(s, 4, 64);
        s += __shfl_xor(s, 8, 64); s += __shfl_xor(s, 16, 64); s += __shfl_xor(s, 32, 64);
        if (l == 0) red[wv][c] = s;
    }
    __syncthreads();
    if (t < 32) {
        float tot = red[0][t] + red[1][t] + red[2][t] + red[3][t];
        pooled2[((size_t)b * 4 + q) * CCH + cc * 32 + t] = tot;
    }
}

// ---------------- coeff2: routing coefficients from quarter-partials ----------------
__global__ __launch_bounds__(128) void coeff2_kernel(const float* __restrict__ pooled2,
                                                     const float* __restrict__ fc_w,
                                                     const float* __restrict__ fc_b,
                                                     float* __restrict__ coeffs) {
    int t = threadIdx.x;
    int b = t >> 2, k = t & 3;
    const float4* p0 = (const float4*)(pooled2 + ((size_t)b * 4 + 0) * CCH);
    const float4* p1 = (const float4*)(pooled2 + ((size_t)b * 4 + 1) * CCH);
    const float4* p2 = (const float4*)(pooled2 + ((size_t)b * 4 + 2) * CCH);
    const float4* p3 = (const float4*)(pooled2 + ((size_t)b * 4 + 3) * CCH);
    const float4* w4 = (const float4*)(fc_w + k * CCH);
    float acc = 0.f;
#pragma unroll
    for (int j = 0; j < 32; ++j) {
        float4 a0 = p0[j], a1 = p1[j], a2 = p2[j], a3 = p3[j], w = w4[j];
        acc += (a0.x + a1.x + a2.x + a3.x) * w.x;
        acc += (a0.y + a1.y + a2.y + a3.y) * w.y;
        acc += (a0.z + a1.z + a2.z + a3.z) * w.z;
        acc += (a0.w + a1.w + a2.w + a3.w) * w.w;
    }
    float dot = fc_b[k] + acc * (1.0f / 4096.0f);
    float s = 1.0f / (1.0f + expf(-dot));
    float m = s;
    m = fmaxf(m, __shfl_xor(m, 1, 64));
    m = fmaxf(m, __shfl_xor(m, 2, 64));
    float e = expf(s - m);
    float sum = e;
    sum += __shfl_xor(sum, 1, 64);
    sum += __shfl_xor(sum, 2, 64);
    coeffs[t] = e / sum;
}

// ---------------- Kernel W: mix -> bf16 in conv tile layout (shared by both paths) ----
// wmix per b: [p(12)][dx(3)][wr(2)][mt(4)][lane(64)][8 bf16]  (1024 B tiles)
__global__ __launch_bounds__(256) void mix_kernel(const float* __restrict__ kernels,
                                                  const float* __restrict__ coeffs,
                                                  unsigned short* __restrict__ wmix) {
    extern __shared__ float klds[];   // 4*4624 = 18496 floats (73984 B)
    int bid = blockIdx.x;
    int bq = bid & 15;
    int rest = bid >> 4;              // 0..31
    int cog = rest & 7, cc = rest >> 3;
    int t = threadIdx.x;

    const int KSTR = CCH * CCH * 9;
    for (int s = t; s < 4 * 16 * 288; s += 256) {
        int k = s / 4608;
        int rem = s - k * 4608;
        int co = rem / 288;
        int i = rem - co * 288;            // ci*9 + tap
        klds[k * 4624 + co * 289 + i] =
            kernels[(size_t)k * KSTR + ((size_t)(cog * 16 + co) * CCH + cc * 32) * 9 + i];
    }
    __syncthreads();

    int wr = cog >> 2, mt = cog & 3;
#pragma unroll
    for (int jb = 0; jb < 2; ++jb) {
        int b = bq + jb * 16;
        float cf0 = coeffs[b * 4 + 0];
        float cf1 = coeffs[b * 4 + 1];
        float cf2 = coeffs[b * 4 + 2];
        float cf3 = coeffs[b * 4 + 3];
        for (int s = t; s < 576; s += 256) {
            int lane = s & 63;
            int tj = s >> 6;                 // 0..8
            int dy = tj / 3, dx = tj - dy * 3;
            int col = lane & 15;             // co_local
            int ci8 = (lane >> 4) * 8;
            unsigned short vals[8];
#pragma unroll
            for (int e = 0; e < 8; ++e) {
                int idx = col * 289 + (ci8 + e) * 9 + dy * 3 + dx;
                float v = cf0 * klds[idx]
                        + cf1 * klds[4624 + idx]
                        + cf2 * klds[2 * 4624 + idx]
                        + cf3 * klds[3 * 4624 + idx];
                vals[e] = f2bf(v);
            }
            int p = cc * 3 + dy;
            size_t off = (size_t)b * 147456
                       + ((size_t)((p * 3 + dx) * 2 + wr) * 4 + mt) * 512 + (size_t)lane * 8;
            *(s16x8*)&wmix[off] = *(const s16x8*)vals;
        }
    }
}

// ---------------- conv (big path): global_load_lds-staged xs ----------------
// grid = 512 (32 b x 16 ytiles of 4 rows), 512 threads (8 waves: wr2 x wc4).
// xs double-buffered [6 rows][72 cols][4 oct][8 bf16] = 27648 B each; staged by
// 27 global_load_lds (1024 B) per phase from pre-swizzled xws sources, issued
// BEFORE the 9-tap compute; __syncthreads drains vmcnt. Halo rows/cols read a
// 4KB zero block. Oct-XOR swizzle -> 2-way banks (free) on ds_read_b128.
__global__ __launch_bounds__(512, 4) void conv_kernel(const unsigned short* __restrict__ xws,
                                                      const unsigned short* __restrict__ wmix,
                                                      const unsigned short* __restrict__ zeros,
                                                      float* __restrict__ out) {
    __shared__ unsigned short xs[2][13824];   // 2 x 27648 B

    int bid = blockIdx.x;
    int b = bid & 31, ytile = bid >> 5;
    int y0 = ytile * 4;
    int t = threadIdx.x;
    int l = t & 63, w = t >> 6;
    int wr = w >> 2, wc = w & 3;
    int l15 = l & 15, g = l >> 4;

    const unsigned short* wb = wmix + (size_t)b * 147456;

    // staging source precompute: inst s = w + 8k (issued iff s < 27)
    const unsigned short* psrc[4];
    int pvalid = 0;
#pragma unroll
    for (int k = 0; k < 4; ++k) {
        int s = w + k * 8;
        int slot = s * 64 + l;
        int oct_s = slot & 3;
        int cp = (slot >> 2) % 72;      // stored col 0..71, gx = cp-2
        int row = (slot >> 2) / 72;     // 0..5, gy = y0+row-1
        int gy = y0 + row - 1;
        int gx = cp - 2;
        int octL = oct_s ^ ((cp >> 1) & 3);
        if (s < 27 && (unsigned)gy < 64u && (unsigned)gx < 64u) {
            psrc[k] = xws + (((size_t)b * 4 * 64 + gy) * 64 + gx) * 32 + octL * 8;
            pvalid |= (1 << k);
        } else {
            psrc[k] = zeros + l * 8;
        }
    }

    // ---- prologue: stage cc=0 into buf 0 ----
#pragma unroll
    for (int k = 0; k < 4; ++k) {
        int s = w + k * 8;
        if (s < 27) {
            __builtin_amdgcn_global_load_lds(
                (const __attribute__((address_space(1))) void*)psrc[k],
                (__attribute__((address_space(3))) void*)(&xs[0][0] + s * 512 + l * 8), 16, 0, 0);
        }
    }
    __syncthreads();

    f32x4 acc[4][4] = {};

    for (int cc = 0; cc < 4; ++cc) {
        const unsigned short* xcur = &xs[cc & 1][0];
        // ---- issue next phase's staging into the other buffer (latency hides under MFMA) ----
        if (cc < 3) {
            unsigned short* xnxt = &xs[(cc + 1) & 1][0];
#pragma unroll
            for (int k = 0; k < 4; ++k) {
                int s = w + k * 8;
                if (s < 27) {
                    const unsigned short* sp = psrc[k]
                        + (((pvalid >> k) & 1) ? (size_t)(cc + 1) * 131072 : (size_t)0);
                    __builtin_amdgcn_global_load_lds(
                        (const __attribute__((address_space(1))) void*)sp,
                        (__attribute__((address_space(3))) void*)(xnxt + s * 512 + l * 8), 16, 0, 0);
                }
            }
        }
        // ---- compute: 3 dy x 3 dx, A from global (coalesced, L1-hot), B from LDS ----
#pragma unroll
        for (int dy = 0; dy < 3; ++dy) {
            int p = cc * 3 + dy;
            int xrow = wc + dy;
#pragma unroll
            for (int dx = 0; dx < 3; ++dx) {
                const unsigned short* wt = wb + ((size_t)((p * 3 + dx) * 2 + wr) * 4) * 512
                                              + (size_t)l * 8;
                s16x8 a[4];
#pragma unroll
                for (int mt = 0; mt < 4; ++mt)
                    a[mt] = *(const s16x8*)(wt + mt * 512);
#pragma unroll
                for (int nt = 0; nt < 4; ++nt) {
                    int cp = nt * 16 + l15 + dx + 1;   // stored col
                    s16x8 bf = *(const s16x8*)&xcur[(size_t)(xrow * 72 + cp) * 32
                                                    + (g ^ ((cp >> 1) & 3)) * 8];
#pragma unroll
                    for (int mt = 0; mt < 4; ++mt)
                        acc[mt][nt] = __builtin_amdgcn_mfma_f32_16x16x32_bf16(
                            a[mt], bf, acc[mt][nt], 0, 0, 0);
                }
            }
        }
        __syncthreads();   // drains vmcnt: next buffer staged; current reads quiesced
    }

    // ---- epilogue ----
    int gy = y0 + wc;
#pragma unroll
    for (int mt = 0; mt < 4; ++mt)
#pragma unroll
        for (int nt = 0; nt < 4; ++nt) {
            int gxo = nt * 16 + l15;
#pragma unroll
            for (int j = 0; j < 4; ++j) {
                int co = wr * 64 + mt * 16 + g * 4 + j;
                out[(((size_t)b * CCH + co) * 64 + gy) * 64 + gxo] = acc[mt][nt][j];
            }
        }
}

// ================= FALLBACK PATH (round-6, proven) =================

__global__ __launch_bounds__(256) void pool_kernel(const float* __restrict__ x,
                                                   float* __restrict__ pooled) {
    int blk = blockIdx.x;
    const float4* x4 = (const float4*)(x + (size_t)blk * 4096);
    int t = threadIdx.x;
    float s = 0.f;
#pragma unroll
    for (int j = 0; j < 4; ++j) {
        float4 v = x4[j * 256 + t];
        s += v.x + v.y + v.z + v.w;
    }
#pragma unroll
    for (int off = 32; off; off >>= 1) s += __shfl_xor(s, off, 64);
    __shared__ float red[4];
    if ((t & 63) == 0) red[t >> 6] = s;
    __syncthreads();
    if (t == 0) {
        float tot = red[0] + red[1] + red[2] + red[3];
        pooled[blk] = tot * (1.0f / 4096.0f);
    }
}

__global__ __launch_bounds__(128) void coeff_kernel(const float* __restrict__ pooled,
                                                    const float* __restrict__ fc_w,
                                                    const float* __restrict__ fc_b,
                                                    float* __restrict__ coeffs) {
    int t = threadIdx.x;
    int b = t >> 2, k = t & 3;
    const float4* p4 = (const float4*)(pooled + b * CCH);
    const float4* w4 = (const float4*)(fc_w + k * CCH);
    float dot = fc_b[k];
#pragma unroll
    for (int j = 0; j < 32; ++j) {
        float4 a = p4[j], w = w4[j];
        dot += a.x * w.x + a.y * w.y + a.z * w.z + a.w * w.w;
    }
    float s = 1.0f / (1.0f + expf(-dot));
    float m = s;
    m = fmaxf(m, __shfl_xor(m, 1, 64));
    m = fmaxf(m, __shfl_xor(m, 2, 64));
    float e = expf(s - m);
    float sum = e;
    sum += __shfl_xor(sum, 1, 64);
    sum += __shfl_xor(sum, 2, 64);
    coeffs[t] = e / sum;
}

typedef __attribute__((ext_vector_type(4))) unsigned int u32x4b;
__global__ __launch_bounds__(512, 4) void conv_fb_kernel(const float* __restrict__ x,
                                                         const unsigned short* __restrict__ wmix,
                                                         float* __restrict__ out) {
    __shared__ unsigned short xsb[6 * 66 * 40];

    int bid = blockIdx.x;
    int b = bid & 31, ytile = bid >> 5;
    int y0 = ytile * 4;
    int t = threadIdx.x;
    int l = t & 63, w = t >> 6;
    int wr = w >> 2, wc = w & 3;
    int l15 = l & 15, g = l >> 4;

    const unsigned short* wb = wmix + (size_t)b * 147456;

    if (t < 240) {
        int row = t / 40;
        int colsel = (t / 20) & 1;
        int cpart = t % 20;
        *(unsigned*)&xsb[(row * 66 + colsel * 65) * 40 + cpart * 2] = 0u;
    }

    f32x4 acc[4][4] = {};

    for (int cc = 0; cc < 4; ++cc) {
        __syncthreads();
#pragma unroll
        for (int i = 0; i < 3; ++i) {
            int slot = w + i * 8;
            int row = slot >> 2, colhi = slot & 3;
            int gx = colhi * 16 + l15;
            int gy = y0 + row - 1;
            float v[8];
#pragma unroll
            for (int j = 0; j < 8; ++j) v[j] = 0.f;
            if ((unsigned)gy < 64u) {
                const float* xp = x + (((size_t)b * CCH + cc * 32 + g * 8) * 64 + gy) * 64 + gx;
#pragma unroll
                for (int j = 0; j < 8; ++j) v[j] = xp[(size_t)j * 4096];
            }
            unsigned pk[4];
#pragma unroll
            for (int j = 0; j < 4; ++j)
                pk[j] = (unsigned)f2bf(v[2 * j]) | ((unsigned)f2bf(v[2 * j + 1]) << 16);
            u32x4b qv; qv[0] = pk[0]; qv[1] = pk[1]; qv[2] = pk[2]; qv[3] = pk[3];
            *(u32x4b*)&xsb[(size_t)(row * 66 + gx + 1) * 40 + g * 8] = qv;
        }
        __syncthreads();
#pragma unroll
        for (int dy = 0; dy < 3; ++dy) {
            int p = cc * 3 + dy;
            int xrow = wc + dy;
#pragma unroll
            for (int dx = 0; dx < 3; ++dx) {
                const unsigned short* wt = wb + ((size_t)((p * 3 + dx) * 2 + wr) * 4) * 512
                                              + (size_t)l * 8;
                s16x8 a[4];
#pragma unroll
                for (int mt = 0; mt < 4; ++mt)
                    a[mt] = *(const s16x8*)(wt + mt * 512);
#pragma unroll
                for (int nt = 0; nt < 4; ++nt) {
                    s16x8 bf = *(const s16x8*)&xsb[(size_t)(xrow * 66 + nt * 16 + l15 + dx) * 40 + g * 8];
#pragma unroll
                    for (int mt = 0; mt < 4; ++mt)
                        acc[mt][nt] = __builtin_amdgcn_mfma_f32_16x16x32_bf16(
                            a[mt], bf, acc[mt][nt], 0, 0, 0);
                }
            }
        }
    }

    int gy = y0 + wc;
#pragma unroll
    for (int mt = 0; mt < 4; ++mt)
#pragma unroll
        for (int nt = 0; nt < 4; ++nt) {
            int gxo = nt * 16 + l15;
#pragma unroll
            for (int j = 0; j < 4; ++j) {
                int co = wr * 64 + mt * 16 + g * 4 + j;
                out[(((size_t)b * CCH + co) * 64 + gy) * 64 + gxo] = acc[mt][nt][j];
            }
        }
}

extern "C" void kernel_launch(void* const* d_in, const int* in_sizes, int n_in,
                              void* d_out, int out_size, void* d_ws, size_t ws_size,
                              hipStream_t stream) {
    const float* x       = (const float*)d_in[0];   // [32,128,64,64]
    const float* kernels = (const float*)d_in[1];   // [4,128,128,3,3]
    const float* fc_w    = (const float*)d_in[2];   // [4,128]
    const float* fc_b    = (const float*)d_in[3];   // [4]
    float* out = (float*)d_out;

    hipFuncSetAttribute((const void*)mix_kernel,
                        hipFuncAttributeMaxDynamicSharedMemorySize, 73984);

    const size_t NEED = 16777216ull + 33554432ull;   // wmix region end + xws
    if (ws_size >= NEED) {
        float* pooled2        = (float*)d_ws;                                   // 64 KB
        float* coeffs         = (float*)((char*)d_ws + 65536);                  // 512 B
        unsigned short* zeros = (unsigned short*)((char*)d_ws + 66560);         // 4 KB
        unsigned short* wmix  = (unsigned short*)((char*)d_ws + 73728);         // 9.44 MB
        unsigned short* xws   = (unsigned short*)((char*)d_ws + 16777216);      // 33.55 MB

        prep_kernel<<<513, 256, 0, stream>>>(x, xws, pooled2, zeros);
        coeff2_kernel<<<1, 128, 0, stream>>>(pooled2, fc_w, fc_b, coeffs);
        mix_kernel<<<512, 256, 73984, stream>>>(kernels, coeffs, wmix);
        conv_kernel<<<512, 512, 0, stream>>>(xws, wmix, zeros, out);
    } else {
        float* pooled = (float*)d_ws;
        float* coeffs = pooled + BSZ * CCH;
        unsigned short* wmix = (unsigned short*)((char*)d_ws + 32768);

        pool_kernel<<<BSZ * CCH, 256, 0, stream>>>(x, pooled);
        coeff_kernel<<<1, 128, 0, stream>>>(pooled, fc_w, fc_b, coeffs);
        mix_kernel<<<512, 256, 73984, stream>>>(kernels, coeffs, wmix);
        conv_fb_kernel<<<512, 512, 0, stream>>>(x, wmix, out);
    }
}